// Round 1
// baseline (12127.353 us; speedup 1.0000x reference)
//
#include <hip/hip_runtime.h>

typedef __attribute__((ext_vector_type(8))) short s16x8;
typedef __attribute__((ext_vector_type(4))) float f32x4;

#define LSEQ 128
#define NJT 16
#define NFRAG 28                       // frags per j-tile: r,z,hn x 9ks + in x 1
#define WFRAG_SHORTS (NJT * NFRAG * 512)   // 229376 shorts

__device__ __forceinline__ unsigned short f2b(float f) {
  unsigned u = __float_as_uint(f);
  u += 0x7FFFu + ((u >> 16) & 1u);     // round-to-nearest-even bf16
  return (unsigned short)(u >> 16);
}

// Pack W into MFMA A-fragment order, augmented:
//   k in [0,256): W_hh[row][k]
//   k == 256   : x-coefficient  (W_ih[row] for r,z; 0 for hn; W_ih[row_n] for "in" tile)
//   k == 257   : bias           (b_ih+b_hh for r,z; b_hh for hn; b_ih for "in")
// Fragment (jt, f): f = g*9+ks (g=0 r,1 z,2 hn), f==27: "in" tile (ks==8 only).
// Element (lane, e): A-row = jt*16 + (lane&15), k = ks*32 + (lane>>4)*8 + e.
__global__ void gru_prep(const float* __restrict__ Wih, const float* __restrict__ Whh,
                         const float* __restrict__ bih, const float* __restrict__ bhh,
                         const float* __restrict__ Wfc,
                         unsigned short* __restrict__ wfrag,
                         unsigned short* __restrict__ wfc16) {
  int t = blockIdx.x * 256 + threadIdx.x;
  if (t < WFRAG_SHORTS) {
    int e = t & 7, lane = (t >> 3) & 63, fl = t >> 9;
    int f = fl % NFRAG, jt = fl / NFRAG;
    int m = lane & 15, gl = lane >> 4;
    float val = 0.f;
    if (f < 27) {
      int g = f / 9, ks = f % 9;
      int row = g * 256 + jt * 16 + m;
      int k = ks * 32 + gl * 8 + e;
      if (k < 256) val = Whh[row * 256 + k];
      else if (k == 256) val = (g == 2) ? 0.f : Wih[row];
      else if (k == 257) val = (g == 2) ? bhh[row] : (bih[row] + bhh[row]);
    } else {                            // "in" tile: i_n = x*W_ih_n + b_ih_n
      int row = 512 + jt * 16 + m;
      int k = 256 + gl * 8 + e;
      if (k == 256) val = Wih[row];
      else if (k == 257) val = bih[row];
    }
    wfrag[t] = f2b(val);
  } else if (t < WFRAG_SHORTS + 4096) { // W_fc -> bf16 [16][256] row-major
    int t2 = t - WFRAG_SHORTS;
    wfc16[t2] = f2b(Wfc[t2]);
  }
}

// LDS h layout: row-major [128 rows][256 shorts], column rotated by (row&15)*32
// shorts so stride-512B fragment reads spread across banks (2-way, free).
__device__ __forceinline__ int haddr(int lrow, int col_s) {
  return lrow * 256 + ((col_s + ((lrow & 15) << 5)) & 255);
}

__global__ __launch_bounds__(512, 1) void gru_main(
    const int* __restrict__ x,
    const unsigned short* __restrict__ wfrag,
    const unsigned short* __restrict__ wfc16,
    const float* __restrict__ bfc,
    float* __restrict__ out) {
  __shared__ unsigned short hl[128 * 256];   // 64 KiB exactly

  const int tid = threadIdx.x;
  const int lane = tid & 63;
  const int wv = tid >> 6;      // wave 0..7
  const int q = lane >> 4;      // 0..3
  const int b = lane & 15;      // batch col within 16-tile / A-row within tile
  const int bbase = blockIdx.x * 128;

  { // zero h0
    unsigned int* p = (unsigned int*)hl;
#pragma unroll
    for (int r = 0; r < 32; ++r) p[tid + r * 512] = 0u;
  }

  // resident W_fc A-frags + b_fc
  s16x8 wfc[8];
#pragma unroll
  for (int ks = 0; ks < 8; ++ks)
    wfc[ks] = *(const s16x8*)&wfc16[b * 256 + ks * 32 + q * 8];
  float bfc4[4];
#pragma unroll
  for (int r = 0; r < 4; ++r) bfc4[r] = bfc[q * 4 + r];

  float lp = 0.f;
  unsigned int stash[2][8][2];
  __syncthreads();

#pragma unroll 1
  for (int i = 0; i < LSEQ; ++i) {
    // launder W pointer so per-step fragment loads are not hoisted out of the loop
    unsigned long wfu = (unsigned long)wfrag;
    asm volatile("" : "+s"(wfu));
    const unsigned short* wf = (const unsigned short*)wfu;

    // x inputs for this step (x_in = x[:, i-1], 0 at i==0)
    float xin8[8];
#pragma unroll
    for (int bt = 0; bt < 8; ++bt)
      xin8[bt] = (i > 0) ? (float)x[(bbase + bt * 16 + b) * LSEQ + i - 1] : 0.f;

#pragma unroll
    for (int ph = 0; ph < 2; ++ph) {
      const int jt = wv + 8 * ph;
      s16x8 wA[NFRAG];
#pragma unroll
      for (int f = 0; f < NFRAG; ++f)
        wA[f] = *(const s16x8*)&wf[((jt * NFRAG + f) * 64 + lane) * 8];

#pragma unroll
      for (int bt = 0; bt < 8; ++bt) {
        const int lrow = bt * 16 + b;
        // x/bias B-frag for the K=256..287 tile: k256=x_in, k257=1.0
        s16x8 xf = {0, 0, 0, 0, 0, 0, 0, 0};
        if (q == 0) { xf[0] = (short)f2b(xin8[bt]); xf[1] = (short)0x3F80; }
        // h_prev for this (bt, j-tile): 4 contiguous bf16
        const uint2 hp = *(const uint2*)&hl[haddr(lrow, 16 * jt + 4 * q)];

        f32x4 aR = {0, 0, 0, 0}, aZ = {0, 0, 0, 0}, aH = {0, 0, 0, 0}, aI = {0, 0, 0, 0};
#pragma unroll
        for (int ks = 0; ks < 8; ++ks) {
          s16x8 hb = *(const s16x8*)&hl[haddr(lrow, 32 * ks + 8 * q)];
          aR = __builtin_amdgcn_mfma_f32_16x16x32_bf16(wA[ks],      hb, aR, 0, 0, 0);
          aZ = __builtin_amdgcn_mfma_f32_16x16x32_bf16(wA[9 + ks],  hb, aZ, 0, 0, 0);
          aH = __builtin_amdgcn_mfma_f32_16x16x32_bf16(wA[18 + ks], hb, aH, 0, 0, 0);
        }
        aR = __builtin_amdgcn_mfma_f32_16x16x32_bf16(wA[8],  xf, aR, 0, 0, 0);
        aZ = __builtin_amdgcn_mfma_f32_16x16x32_bf16(wA[17], xf, aZ, 0, 0, 0);
        aH = __builtin_amdgcn_mfma_f32_16x16x32_bf16(wA[26], xf, aH, 0, 0, 0);
        aI = __builtin_amdgcn_mfma_f32_16x16x32_bf16(wA[27], xf, aI, 0, 0, 0);

        float hpv[4] = {__uint_as_float(hp.x << 16), __uint_as_float(hp.x & 0xFFFF0000u),
                        __uint_as_float(hp.y << 16), __uint_as_float(hp.y & 0xFFFF0000u)};
        float hv[4];
#pragma unroll
        for (int r = 0; r < 4; ++r) {
          float rr = 1.f / (1.f + __expf(-aR[r]));
          float zz = 1.f / (1.f + __expf(-aZ[r]));
          float t2 = __expf(2.f * (aI[r] + rr * aH[r]));
          float nn = (t2 - 1.f) / (t2 + 1.f);
          hv[r] = nn + zz * (hpv[r] - nn);     // (1-z)*n + z*h
        }
        stash[ph][bt][0] = (unsigned)f2b(hv[0]) | ((unsigned)f2b(hv[1]) << 16);
        stash[ph][bt][1] = (unsigned)f2b(hv[2]) | ((unsigned)f2b(hv[3]) << 16);
      }
    }

    __syncthreads();   // all reads of h_{i-1} complete
#pragma unroll
    for (int ph = 0; ph < 2; ++ph) {
      const int jt = wv + 8 * ph;
#pragma unroll
      for (int bt = 0; bt < 8; ++bt) {
        const int lrow = bt * 16 + b;
        *(uint2*)&hl[haddr(lrow, 16 * jt + 4 * q)] =
            make_uint2(stash[ph][bt][0], stash[ph][bt][1]);
      }
    }
    __syncthreads();   // h_i visible

    { // FC + log_softmax + gather; wave wv handles batch tile bt == wv
      const int lrow = wv * 16 + b;
      const int grow = bbase + lrow;
      f32x4 fa = {bfc4[0], bfc4[1], bfc4[2], bfc4[3]};
#pragma unroll
      for (int ks = 0; ks < 8; ++ks) {
        s16x8 hb = *(const s16x8*)&hl[haddr(lrow, 32 * ks + 8 * q)];
        fa = __builtin_amdgcn_mfma_f32_16x16x32_bf16(wfc[ks], hb, fa, 0, 0, 0);
      }
      int tgt = x[grow * LSEQ + i];
      float l0 = fa[0], l1 = fa[1], l2 = fa[2], l3 = fa[3];
      float mx = fmaxf(fmaxf(l0, l1), fmaxf(l2, l3));
      mx = fmaxf(mx, __shfl_xor(mx, 16));
      mx = fmaxf(mx, __shfl_xor(mx, 32));
      float se = __expf(l0 - mx) + __expf(l1 - mx) + __expf(l2 - mx) + __expf(l3 - mx);
      se += __shfl_xor(se, 16);
      se += __shfl_xor(se, 32);
      float v01 = (tgt & 1) ? l1 : l0;
      float v23 = (tgt & 1) ? l3 : l2;
      float vs = (tgt & 2) ? v23 : v01;
      float contrib = (q == (tgt >> 2)) ? vs : 0.f;
      contrib += __shfl_xor(contrib, 16);
      contrib += __shfl_xor(contrib, 32);
      lp += contrib - mx - __logf(se);
    }
  }

  if (q == 0) out[bbase + wv * 16 + b] = lp;
}

extern "C" void kernel_launch(void* const* d_in, const int* in_sizes, int n_in,
                              void* d_out, int out_size, void* d_ws, size_t ws_size,
                              hipStream_t stream) {
  (void)in_sizes; (void)n_in; (void)out_size; (void)ws_size;
  const int*   x   = (const int*)d_in[0];
  const float* Wih = (const float*)d_in[1];
  const float* Whh = (const float*)d_in[2];
  const float* bih = (const float*)d_in[3];
  const float* bhh = (const float*)d_in[4];
  const float* Wfc = (const float*)d_in[5];
  const float* bfc = (const float*)d_in[6];
  float* out = (float*)d_out;

  unsigned short* wfrag = (unsigned short*)d_ws;
  unsigned short* wfc16 = wfrag + WFRAG_SHORTS;

  gru_prep<<<dim3(912), dim3(256), 0, stream>>>(Wih, Whh, bih, bhh, Wfc, wfrag, wfc16);
  gru_main<<<dim3(256), dim3(512), 0, stream>>>(x, wfrag, wfc16, bfc, out);
}

// Round 2
// 4279.329 us; speedup vs baseline: 2.8339x; 2.8339x over previous
//
#include <hip/hip_runtime.h>

typedef __attribute__((ext_vector_type(8))) short s16x8;
typedef __attribute__((ext_vector_type(4))) float f32x4;

#define BATCH 32768
#define LSEQ 128
#define NJT 16
#define NFRAG 28                           // frags per j-tile: r,z,hn x 9ks + in x 1
#define WFRAG_SHORTS (NJT * NFRAG * 512)   // 229376 shorts
#define WFC_SHORTS 4096
#define XT_OFF_BYTES ((WFRAG_SHORTS + WFC_SHORTS) * 2)        // 466944
#define WS_NEED_XT (XT_OFF_BYTES + BATCH * LSEQ * 4)          // ~16.45 MB

__device__ __forceinline__ unsigned short f2b(float f) {
  unsigned u = __float_as_uint(f);
  u += 0x7FFFu + ((u >> 16) & 1u);     // round-to-nearest-even bf16
  return (unsigned short)(u >> 16);
}

// Pack W into MFMA A-fragment order, augmented K: k256=x coeff, k257=bias.
// Fragment (jt, f): f = g*9+ks (g=0 r,1 z,2 hn), f==27: "in" tile (ks==8 only).
// Element (lane, e): A-row = jt*16 + (lane&15), k = ks*32 + (lane>>4)*8 + e.
__global__ void gru_prep(const float* __restrict__ Wih, const float* __restrict__ Whh,
                         const float* __restrict__ bih, const float* __restrict__ bhh,
                         const float* __restrict__ Wfc,
                         unsigned short* __restrict__ wfrag,
                         unsigned short* __restrict__ wfc16) {
  int t = blockIdx.x * 256 + threadIdx.x;
  if (t < WFRAG_SHORTS) {
    int e = t & 7, lane = (t >> 3) & 63, fl = t >> 9;
    int f = fl % NFRAG, jt = fl / NFRAG;
    int m = lane & 15, gl = lane >> 4;
    float val = 0.f;
    if (f < 27) {
      int g = f / 9, ks = f % 9;
      int row = g * 256 + jt * 16 + m;
      int k = ks * 32 + gl * 8 + e;
      if (k < 256) val = Whh[row * 256 + k];
      else if (k == 256) val = (g == 2) ? 0.f : Wih[row];
      else if (k == 257) val = (g == 2) ? bhh[row] : (bih[row] + bhh[row]);
    } else {                            // "in" tile: i_n = x*W_ih_n + b_ih_n
      int row = 512 + jt * 16 + m;
      int k = 256 + gl * 8 + e;
      if (k == 256) val = Wih[row];
      else if (k == 257) val = bih[row];
    }
    wfrag[t] = f2b(val);
  } else if (t < WFRAG_SHORTS + WFC_SHORTS) { // W_fc -> bf16 [16][256] row-major
    int t2 = t - WFRAG_SHORTS;
    wfc16[t2] = f2b(Wfc[t2]);
  }
}

// Tiled transpose x[B][L] -> xT[L][B] so per-step column reads are coalesced.
__global__ void x_transpose(const int* __restrict__ x, int* __restrict__ xT) {
  __shared__ int tile[32][33];
  int l0 = blockIdx.x * 32, b0 = blockIdx.y * 32;
  for (int r = threadIdx.y; r < 32; r += 8)
    tile[r][threadIdx.x] = x[(b0 + r) * LSEQ + l0 + threadIdx.x];
  __syncthreads();
  for (int r = threadIdx.y; r < 32; r += 8)
    xT[(l0 + r) * BATCH + b0 + threadIdx.x] = tile[threadIdx.x][r];
}

// LDS h layout: [128 rows][256 shorts], column rotated by (row&15)*32 shorts.
__device__ __forceinline__ int haddr(int lrow, int col_s) {
  return lrow * 256 + ((col_s + ((lrow & 15) << 5)) & 255);
}

template <int XT>
__global__ __launch_bounds__(512, 2) void gru_main(
    const int* __restrict__ x, const int* __restrict__ xTr,
    const unsigned short* __restrict__ wfrag,
    const unsigned short* __restrict__ wfc16,
    const float* __restrict__ bfc, float* __restrict__ out) {
  __shared__ unsigned short hl[128 * 256];   // 64 KiB

  const int tid = threadIdx.x;
  const int lane = tid & 63;
  const int wv = tid >> 6;      // wave 0..7
  const int q = lane >> 4;      // 0..3
  const int b = lane & 15;      // batch col within 16-tile / A-row within tile
  const int bbase = blockIdx.x * 128;

  { // zero h0
    unsigned int* p = (unsigned int*)hl;
#pragma unroll
    for (int r = 0; r < 32; ++r) p[tid + r * 512] = 0u;
  }

  float bfc4[4];
#pragma unroll
  for (int r = 0; r < 4; ++r) bfc4[r] = bfc[q * 4 + r];

  float lp = 0.f;
  unsigned int stash[2][8][2];
  __syncthreads();

#pragma unroll 1
  for (int i = 0; i < LSEQ; ++i) {
    // launder pointers so per-step loads are not hoisted/staged across the loop
    unsigned long wfu = (unsigned long)wfrag;
    asm volatile("" : "+s"(wfu));
    const unsigned short* wf = (const unsigned short*)wfu;
    unsigned long wcu = (unsigned long)wfc16;
    asm volatile("" : "+s"(wcu));
    const unsigned short* wc = (const unsigned short*)wcu;

    float xin8[8];
    if (XT) {
#pragma unroll
      for (int bt = 0; bt < 8; ++bt)
        xin8[bt] = (i > 0) ? (float)xTr[(i - 1) * BATCH + bbase + bt * 16 + b] : 0.f;
    } else {
#pragma unroll
      for (int bt = 0; bt < 8; ++bt)
        xin8[bt] = (i > 0) ? (float)x[(bbase + bt * 16 + b) * LSEQ + i - 1] : 0.f;
    }

#pragma unroll
    for (int ph = 0; ph < 2; ++ph) {
      const int jt = wv + 8 * ph;
      const unsigned short* fb = wf + (jt * NFRAG * 64 + lane) * 8;

      f32x4 aR[8], aZ[8], aH[8];
#pragma unroll
      for (int bt = 0; bt < 8; ++bt) {
        aR[bt] = (f32x4){0, 0, 0, 0};
        aZ[bt] = (f32x4){0, 0, 0, 0};
        aH[bt] = (f32x4){0, 0, 0, 0};
      }

      s16x8 wr = *(const s16x8*)(fb);
      s16x8 wz = *(const s16x8*)(fb + 9 * 512);
      s16x8 wh = *(const s16x8*)(fb + 18 * 512);
      s16x8 wi = *(const s16x8*)(fb + 27 * 512);

#pragma unroll 1
      for (int ks = 0; ks < 8; ++ks) {
        // prefetch next K-step's frags (ks==7 fetches the x/bias frags 8/17/26)
        s16x8 wrn = *(const s16x8*)(fb + (ks + 1) * 512);
        s16x8 wzn = *(const s16x8*)(fb + (ks + 10) * 512);
        s16x8 whn = *(const s16x8*)(fb + (ks + 19) * 512);
#pragma unroll
        for (int bt = 0; bt < 8; ++bt) {
          const s16x8 hb = *(const s16x8*)&hl[haddr(bt * 16 + b, 32 * ks + 8 * q)];
          aR[bt] = __builtin_amdgcn_mfma_f32_16x16x32_bf16(wr, hb, aR[bt], 0, 0, 0);
          aZ[bt] = __builtin_amdgcn_mfma_f32_16x16x32_bf16(wz, hb, aZ[bt], 0, 0, 0);
          aH[bt] = __builtin_amdgcn_mfma_f32_16x16x32_bf16(wh, hb, aH[bt], 0, 0, 0);
        }
        wr = wrn; wz = wzn; wh = whn;
      }

      // tail: x/bias K-tile (k256=x_in, k257=1.0) + epilogue, one bt at a time
#pragma unroll
      for (int bt = 0; bt < 8; ++bt) {
        const int lrow = bt * 16 + b;
        s16x8 xf = {0, 0, 0, 0, 0, 0, 0, 0};
        if (q == 0) { xf[0] = (short)f2b(xin8[bt]); xf[1] = (short)0x3F80; }
        const uint2 hp = *(const uint2*)&hl[haddr(lrow, 16 * jt + 4 * q)];

        f32x4 r4 = __builtin_amdgcn_mfma_f32_16x16x32_bf16(wr, xf, aR[bt], 0, 0, 0);
        f32x4 z4 = __builtin_amdgcn_mfma_f32_16x16x32_bf16(wz, xf, aZ[bt], 0, 0, 0);
        f32x4 h4 = __builtin_amdgcn_mfma_f32_16x16x32_bf16(wh, xf, aH[bt], 0, 0, 0);
        f32x4 i4 = __builtin_amdgcn_mfma_f32_16x16x32_bf16(
            wi, xf, (f32x4){0, 0, 0, 0}, 0, 0, 0);

        float hpv[4] = {__uint_as_float(hp.x << 16), __uint_as_float(hp.x & 0xFFFF0000u),
                        __uint_as_float(hp.y << 16), __uint_as_float(hp.y & 0xFFFF0000u)};
        unsigned hw[2];
#pragma unroll
        for (int hlf = 0; hlf < 2; ++hlf) {
          unsigned w = 0;
#pragma unroll
          for (int r = 0; r < 2; ++r) {
            int idx = hlf * 2 + r;
            float rr = 1.f / (1.f + __expf(-r4[idx]));
            float zz = 1.f / (1.f + __expf(-z4[idx]));
            float t2 = __expf(2.f * (i4[idx] + rr * h4[idx]));
            float nn = (t2 - 1.f) / (t2 + 1.f);
            float hv = nn + zz * (hpv[idx] - nn);   // (1-z)*n + z*h
            w |= (unsigned)f2b(hv) << (16 * r);
          }
          hw[hlf] = w;
        }
        stash[ph][bt][0] = hw[0];
        stash[ph][bt][1] = hw[1];
      }
    }

    __syncthreads();   // all reads of h_{i-1} complete
#pragma unroll
    for (int ph = 0; ph < 2; ++ph) {
      const int jt = wv + 8 * ph;
#pragma unroll
      for (int bt = 0; bt < 8; ++bt) {
        const int lrow = bt * 16 + b;
        *(uint2*)&hl[haddr(lrow, 16 * jt + 4 * q)] =
            make_uint2(stash[ph][bt][0], stash[ph][bt][1]);
      }
    }
    __syncthreads();   // h_i visible

    { // FC + log_softmax + gather; wave wv handles batch tile bt == wv
      const int lrow = wv * 16 + b;
      const int grow = bbase + lrow;
      f32x4 fa = {bfc4[0], bfc4[1], bfc4[2], bfc4[3]};
#pragma unroll
      for (int ks = 0; ks < 8; ++ks) {
        s16x8 wfcf = *(const s16x8*)&wc[b * 256 + ks * 32 + q * 8];
        s16x8 hb = *(const s16x8*)&hl[haddr(lrow, 32 * ks + 8 * q)];
        fa = __builtin_amdgcn_mfma_f32_16x16x32_bf16(wfcf, hb, fa, 0, 0, 0);
      }
      int tgt = XT ? xTr[i * BATCH + grow] : x[grow * LSEQ + i];
      float l0 = fa[0], l1 = fa[1], l2 = fa[2], l3 = fa[3];
      float mx = fmaxf(fmaxf(l0, l1), fmaxf(l2, l3));
      mx = fmaxf(mx, __shfl_xor(mx, 16));
      mx = fmaxf(mx, __shfl_xor(mx, 32));
      float se = __expf(l0 - mx) + __expf(l1 - mx) + __expf(l2 - mx) + __expf(l3 - mx);
      se += __shfl_xor(se, 16);
      se += __shfl_xor(se, 32);
      float v01 = (tgt & 1) ? l1 : l0;
      float v23 = (tgt & 1) ? l3 : l2;
      float vs = (tgt & 2) ? v23 : v01;
      float contrib = (q == (tgt >> 2)) ? vs : 0.f;
      contrib += __shfl_xor(contrib, 16);
      contrib += __shfl_xor(contrib, 32);
      lp += contrib - mx - __logf(se);
    }
  }

  if (q == 0) out[bbase + wv * 16 + b] = lp;
}

extern "C" void kernel_launch(void* const* d_in, const int* in_sizes, int n_in,
                              void* d_out, int out_size, void* d_ws, size_t ws_size,
                              hipStream_t stream) {
  (void)in_sizes; (void)n_in; (void)out_size;
  const int*   x   = (const int*)d_in[0];
  const float* Wih = (const float*)d_in[1];
  const float* Whh = (const float*)d_in[2];
  const float* bih = (const float*)d_in[3];
  const float* bhh = (const float*)d_in[4];
  const float* Wfc = (const float*)d_in[5];
  const float* bfc = (const float*)d_in[6];
  float* out = (float*)d_out;

  unsigned short* wfrag = (unsigned short*)d_ws;
  unsigned short* wfc16 = wfrag + WFRAG_SHORTS;
  int* xT = (int*)((char*)d_ws + XT_OFF_BYTES);

  gru_prep<<<dim3(912), dim3(256), 0, stream>>>(Wih, Whh, bih, bhh, Wfc, wfrag, wfc16);

  if (ws_size >= (size_t)WS_NEED_XT) {
    x_transpose<<<dim3(LSEQ / 32, BATCH / 32), dim3(32, 8), 0, stream>>>(x, xT);
    gru_main<1><<<dim3(256), dim3(512), 0, stream>>>(x, xT, wfrag, wfc16, bfc, out);
  } else {
    gru_main<0><<<dim3(256), dim3(512), 0, stream>>>(x, x, wfrag, wfc16, bfc, out);
  }
}

// Round 3
// 2883.310 us; speedup vs baseline: 4.2061x; 1.4842x over previous
//
#include <hip/hip_runtime.h>

typedef __attribute__((ext_vector_type(8))) short s16x8;
typedef __attribute__((ext_vector_type(4))) float f32x4;

#define BATCH 32768
#define LSEQ 128
#define NJT 16
#define NFRAG 28                           // frags per j-tile: r,z,hn x 9ks + in x 1
#define WFRAG_SHORTS (NJT * NFRAG * 512)   // 229376 shorts
#define WFC_SHORTS 4096
#define XT_OFF_BYTES ((WFRAG_SHORTS + WFC_SHORTS) * 2)        // 466944
#define WS_NEED_XT (XT_OFF_BYTES + BATCH * LSEQ * 4)          // ~16.45 MB

#define HBUF_SHORTS (128 * 256)                               // 64 KiB per buffer
#define LDS_BYTES (2 * HBUF_SHORTS * 2 + WFC_SHORTS * 2)      // 139264 B = 136 KiB

__device__ __forceinline__ unsigned short f2b(float f) {
  unsigned u = __float_as_uint(f);
  u += 0x7FFFu + ((u >> 16) & 1u);     // round-to-nearest-even bf16
  return (unsigned short)(u >> 16);
}

// Pack W into MFMA A-fragment order, augmented K: k256=x coeff, k257=bias.
// Fragment (jt, f): f = g*9+ks (g=0 r,1 z,2 hn), f==27: "in" tile (ks==8 only).
// Element (lane, e): A-row = jt*16 + (lane&15), k = ks*32 + (lane>>4)*8 + e.
__global__ void gru_prep(const float* __restrict__ Wih, const float* __restrict__ Whh,
                         const float* __restrict__ bih, const float* __restrict__ bhh,
                         const float* __restrict__ Wfc,
                         unsigned short* __restrict__ wfrag,
                         unsigned short* __restrict__ wfc16) {
  int t = blockIdx.x * 256 + threadIdx.x;
  if (t < WFRAG_SHORTS) {
    int e = t & 7, lane = (t >> 3) & 63, fl = t >> 9;
    int f = fl % NFRAG, jt = fl / NFRAG;
    int m = lane & 15, gl = lane >> 4;
    float val = 0.f;
    if (f < 27) {
      int g = f / 9, ks = f % 9;
      int row = g * 256 + jt * 16 + m;
      int k = ks * 32 + gl * 8 + e;
      if (k < 256) val = Whh[row * 256 + k];
      else if (k == 256) val = (g == 2) ? 0.f : Wih[row];
      else if (k == 257) val = (g == 2) ? bhh[row] : (bih[row] + bhh[row]);
    } else {                            // "in" tile: i_n = x*W_ih_n + b_ih_n
      int row = 512 + jt * 16 + m;
      int k = 256 + gl * 8 + e;
      if (k == 256) val = Wih[row];
      else if (k == 257) val = bih[row];
    }
    wfrag[t] = f2b(val);
  } else if (t < WFRAG_SHORTS + WFC_SHORTS) { // W_fc -> bf16 [16][256] row-major
    int t2 = t - WFRAG_SHORTS;
    wfc16[t2] = f2b(Wfc[t2]);
  }
}

// Tiled transpose x[B][L] -> xT[L][B] so per-step column reads are coalesced.
__global__ void x_transpose(const int* __restrict__ x, int* __restrict__ xT) {
  __shared__ int tile[32][33];
  int l0 = blockIdx.x * 32, b0 = blockIdx.y * 32;
  for (int r = threadIdx.y; r < 32; r += 8)
    tile[r][threadIdx.x] = x[(b0 + r) * LSEQ + l0 + threadIdx.x];
  __syncthreads();
  for (int r = threadIdx.y; r < 32; r += 8)
    xT[(l0 + r) * BATCH + b0 + threadIdx.x] = tile[threadIdx.x][r];
}

// LDS h layout: [row][256 shorts], column rotated by (row&15)*8 shorts so any
// 8 consecutive lanes of a b128 fragment read cover all 32 banks exactly once.
__device__ __forceinline__ int haddr(int lrow, int col_s) {
  return lrow * 256 + ((col_s + ((lrow & 15) << 3)) & 255);
}

__device__ __forceinline__ void gate_epi(const f32x4& r4, const f32x4& z4,
                                         const f32x4& h4, const f32x4& i4,
                                         uint2 hp, unsigned& w0, unsigned& w1) {
  float hpv[4] = {__uint_as_float(hp.x << 16), __uint_as_float(hp.x & 0xFFFF0000u),
                  __uint_as_float(hp.y << 16), __uint_as_float(hp.y & 0xFFFF0000u)};
  unsigned w[2];
#pragma unroll
  for (int hlf = 0; hlf < 2; ++hlf) {
    unsigned acc = 0;
#pragma unroll
    for (int r = 0; r < 2; ++r) {
      int idx = hlf * 2 + r;
      float rr = 1.f / (1.f + __expf(-r4[idx]));
      float zz = 1.f / (1.f + __expf(-z4[idx]));
      float t2 = __expf(2.f * (i4[idx] + rr * h4[idx]));
      float nn = (t2 - 1.f) / (t2 + 1.f);
      float hv = nn + zz * (hpv[idx] - nn);   // (1-z)*n + z*h
      acc |= (unsigned)f2b(hv) << (16 * r);
    }
    w[hlf] = acc;
  }
  w0 = w[0]; w1 = w[1];
}

template <int XT>
__global__ __attribute__((amdgpu_waves_per_eu(2, 2))) __launch_bounds__(512)
void gru_main(const int* __restrict__ x, const int* __restrict__ xTr,
              const unsigned short* __restrict__ wfrag,
              const unsigned short* __restrict__ wfc16,
              const float* __restrict__ bfc, float* __restrict__ out) {
  extern __shared__ unsigned short smem_us[];
  unsigned short* h0 = smem_us;                    // 64 KiB
  unsigned short* h1 = smem_us + HBUF_SHORTS;      // 64 KiB
  unsigned short* wl = smem_us + 2 * HBUF_SHORTS;  // 8 KiB W_fc, swizzled

  const int tid = threadIdx.x;
  const int lane = tid & 63;
  const int wv = tid >> 6;      // wave 0..7
  const int q = lane >> 4;      // 0..3
  const int b = lane & 15;
  const int bbase = blockIdx.x * 128;
  const int jt0 = wv, jt1 = wv + 8;

  { // zero h0 (h1 is fully written in step 0 before any read)
    unsigned int* p = (unsigned int*)h0;
#pragma unroll
    for (int r = 0; r < 32; ++r) p[tid + r * 512] = 0u;
  }
  // copy W_fc into LDS with the same rot-8 swizzle (row = class m)
  for (int t = tid; t < WFC_SHORTS; t += 512) {
    int m = t >> 8, col = t & 255;
    wl[haddr(m, col)] = wfc16[t];
  }

  float bfc4[4];
#pragma unroll
  for (int r = 0; r < 4; ++r) bfc4[r] = bfc[q * 4 + r];

  float lp = 0.f;
  __syncthreads();

#pragma unroll 1
  for (int i = 0; i < LSEQ; ++i) {
    const unsigned short* rd = (i & 1) ? h1 : h0;   // h_{i-1}
    unsigned short* wr = (i & 1) ? h0 : h1;         // h_i

    float xin8[8];
    if (XT) {
#pragma unroll
      for (int bt = 0; bt < 8; ++bt)
        xin8[bt] = (i > 0) ? (float)xTr[(i - 1) * BATCH + bbase + bt * 16 + b] : 0.f;
    } else {
#pragma unroll
      for (int bt = 0; bt < 8; ++bt)
        xin8[bt] = (i > 0) ? (float)x[(bbase + bt * 16 + b) * LSEQ + i - 1] : 0.f;
    }

    const unsigned short* fb0 = wfrag + (jt0 * NFRAG * 64 + lane) * 8;
    const unsigned short* fb1 = wfrag + (jt1 * NFRAG * 64 + lane) * 8;

    f32x4 aR0[8], aZ0[8], aH0[8], aR1[8], aZ1[8], aH1[8];
#pragma unroll
    for (int bt = 0; bt < 8; ++bt) {
      aR0[bt] = (f32x4){0, 0, 0, 0}; aZ0[bt] = (f32x4){0, 0, 0, 0};
      aH0[bt] = (f32x4){0, 0, 0, 0}; aR1[bt] = (f32x4){0, 0, 0, 0};
      aZ1[bt] = (f32x4){0, 0, 0, 0}; aH1[bt] = (f32x4){0, 0, 0, 0};
    }

    // single pass over K: stream 6 weight frags per ks from L2, read each
    // h B-frag once, feed 6 MFMAs (both j-tiles x 3 gates)
#pragma unroll 1
    for (int ks = 0; ks < 8; ++ks) {
      s16x8 wr0 = *(const s16x8*)(fb0 + ks * 512);
      s16x8 wz0 = *(const s16x8*)(fb0 + (9 + ks) * 512);
      s16x8 wh0 = *(const s16x8*)(fb0 + (18 + ks) * 512);
      s16x8 wr1 = *(const s16x8*)(fb1 + ks * 512);
      s16x8 wz1 = *(const s16x8*)(fb1 + (9 + ks) * 512);
      s16x8 wh1 = *(const s16x8*)(fb1 + (18 + ks) * 512);
#pragma unroll
      for (int bt = 0; bt < 8; ++bt) {
        const s16x8 hb = *(const s16x8*)&rd[haddr(bt * 16 + b, 32 * ks + 8 * q)];
        aR0[bt] = __builtin_amdgcn_mfma_f32_16x16x32_bf16(wr0, hb, aR0[bt], 0, 0, 0);
        aZ0[bt] = __builtin_amdgcn_mfma_f32_16x16x32_bf16(wz0, hb, aZ0[bt], 0, 0, 0);
        aH0[bt] = __builtin_amdgcn_mfma_f32_16x16x32_bf16(wh0, hb, aH0[bt], 0, 0, 0);
        aR1[bt] = __builtin_amdgcn_mfma_f32_16x16x32_bf16(wr1, hb, aR1[bt], 0, 0, 0);
        aZ1[bt] = __builtin_amdgcn_mfma_f32_16x16x32_bf16(wz1, hb, aZ1[bt], 0, 0, 0);
        aH1[bt] = __builtin_amdgcn_mfma_f32_16x16x32_bf16(wh1, hb, aH1[bt], 0, 0, 0);
      }
    }

    // tail j-tile 0: aug K-tile (k256=x, k257=1) + epilogue + h write
    {
      s16x8 ar = *(const s16x8*)(fb0 + 8 * 512);
      s16x8 az = *(const s16x8*)(fb0 + 17 * 512);
      s16x8 an = *(const s16x8*)(fb0 + 26 * 512);
      s16x8 ai = *(const s16x8*)(fb0 + 27 * 512);
#pragma unroll
      for (int bt = 0; bt < 8; ++bt) {
        const int lrow = bt * 16 + b;
        s16x8 xf = {0, 0, 0, 0, 0, 0, 0, 0};
        if (q == 0) { xf[0] = (short)f2b(xin8[bt]); xf[1] = (short)0x3F80; }
        uint2 hp = *(const uint2*)&rd[haddr(lrow, 16 * jt0 + 4 * q)];
        f32x4 r4 = __builtin_amdgcn_mfma_f32_16x16x32_bf16(ar, xf, aR0[bt], 0, 0, 0);
        f32x4 z4 = __builtin_amdgcn_mfma_f32_16x16x32_bf16(az, xf, aZ0[bt], 0, 0, 0);
        f32x4 h4 = __builtin_amdgcn_mfma_f32_16x16x32_bf16(an, xf, aH0[bt], 0, 0, 0);
        f32x4 i4 = __builtin_amdgcn_mfma_f32_16x16x32_bf16(ai, xf, (f32x4){0, 0, 0, 0}, 0, 0, 0);
        unsigned w0, w1;
        gate_epi(r4, z4, h4, i4, hp, w0, w1);
        *(uint2*)&wr[haddr(lrow, 16 * jt0 + 4 * q)] = make_uint2(w0, w1);
      }
    }
    // tail j-tile 1
    {
      s16x8 ar = *(const s16x8*)(fb1 + 8 * 512);
      s16x8 az = *(const s16x8*)(fb1 + 17 * 512);
      s16x8 an = *(const s16x8*)(fb1 + 26 * 512);
      s16x8 ai = *(const s16x8*)(fb1 + 27 * 512);
#pragma unroll
      for (int bt = 0; bt < 8; ++bt) {
        const int lrow = bt * 16 + b;
        s16x8 xf = {0, 0, 0, 0, 0, 0, 0, 0};
        if (q == 0) { xf[0] = (short)f2b(xin8[bt]); xf[1] = (short)0x3F80; }
        uint2 hp = *(const uint2*)&rd[haddr(lrow, 16 * jt1 + 4 * q)];
        f32x4 r4 = __builtin_amdgcn_mfma_f32_16x16x32_bf16(ar, xf, aR1[bt], 0, 0, 0);
        f32x4 z4 = __builtin_amdgcn_mfma_f32_16x16x32_bf16(az, xf, aZ1[bt], 0, 0, 0);
        f32x4 h4 = __builtin_amdgcn_mfma_f32_16x16x32_bf16(an, xf, aH1[bt], 0, 0, 0);
        f32x4 i4 = __builtin_amdgcn_mfma_f32_16x16x32_bf16(ai, xf, (f32x4){0, 0, 0, 0}, 0, 0, 0);
        unsigned w0, w1;
        gate_epi(r4, z4, h4, i4, hp, w0, w1);
        *(uint2*)&wr[haddr(lrow, 16 * jt1 + 4 * q)] = make_uint2(w0, w1);
      }
    }

    __syncthreads();   // h_i visible; also fences next step's writes into rd

    { // FC + log_softmax + gather; wave wv handles batch tile bt == wv
      const int lrow = wv * 16 + b;
      const int grow = bbase + lrow;
      f32x4 fa = {bfc4[0], bfc4[1], bfc4[2], bfc4[3]};
#pragma unroll
      for (int ks = 0; ks < 8; ++ks) {
        s16x8 wfcf = *(const s16x8*)&wl[haddr(b, 32 * ks + 8 * q)];
        s16x8 hb = *(const s16x8*)&wr[haddr(lrow, 32 * ks + 8 * q)];
        fa = __builtin_amdgcn_mfma_f32_16x16x32_bf16(wfcf, hb, fa, 0, 0, 0);
      }
      int tgt = XT ? xTr[i * BATCH + grow] : x[grow * LSEQ + i];
      float l0 = fa[0], l1 = fa[1], l2 = fa[2], l3 = fa[3];
      float mx = fmaxf(fmaxf(l0, l1), fmaxf(l2, l3));
      mx = fmaxf(mx, __shfl_xor(mx, 16));
      mx = fmaxf(mx, __shfl_xor(mx, 32));
      float se = __expf(l0 - mx) + __expf(l1 - mx) + __expf(l2 - mx) + __expf(l3 - mx);
      se += __shfl_xor(se, 16);
      se += __shfl_xor(se, 32);
      float v01 = (tgt & 1) ? l1 : l0;
      float v23 = (tgt & 1) ? l3 : l2;
      float vs = (tgt & 2) ? v23 : v01;
      float contrib = (q == (tgt >> 2)) ? vs : 0.f;
      contrib += __shfl_xor(contrib, 16);
      contrib += __shfl_xor(contrib, 32);
      lp += contrib - mx - __logf(se);
    }
  }

  if (q == 0) out[bbase + wv * 16 + b] = lp;
}

extern "C" void kernel_launch(void* const* d_in, const int* in_sizes, int n_in,
                              void* d_out, int out_size, void* d_ws, size_t ws_size,
                              hipStream_t stream) {
  (void)in_sizes; (void)n_in; (void)out_size;
  const int*   x   = (const int*)d_in[0];
  const float* Wih = (const float*)d_in[1];
  const float* Whh = (const float*)d_in[2];
  const float* bih = (const float*)d_in[3];
  const float* bhh = (const float*)d_in[4];
  const float* Wfc = (const float*)d_in[5];
  const float* bfc = (const float*)d_in[6];
  float* out = (float*)d_out;

  unsigned short* wfrag = (unsigned short*)d_ws;
  unsigned short* wfc16 = wfrag + WFRAG_SHORTS;
  int* xT = (int*)((char*)d_ws + XT_OFF_BYTES);

  gru_prep<<<dim3(912), dim3(256), 0, stream>>>(Wih, Whh, bih, bhh, Wfc, wfrag, wfc16);

  if (ws_size >= (size_t)WS_NEED_XT) {
    x_transpose<<<dim3(LSEQ / 32, BATCH / 32), dim3(32, 8), 0, stream>>>(x, xT);
    hipFuncSetAttribute((const void*)gru_main<1>,
                        hipFuncAttributeMaxDynamicSharedMemorySize, LDS_BYTES);
    gru_main<1><<<dim3(256), dim3(512), LDS_BYTES, stream>>>(x, xT, wfrag, wfc16, bfc, out);
  } else {
    hipFuncSetAttribute((const void*)gru_main<0>,
                        hipFuncAttributeMaxDynamicSharedMemorySize, LDS_BYTES);
    gru_main<0><<<dim3(256), dim3(512), LDS_BYTES, stream>>>(x, x, wfrag, wfc16, bfc, out);
  }
}

// Round 4
// 1846.874 us; speedup vs baseline: 6.5664x; 1.5612x over previous
//
#include <hip/hip_runtime.h>

typedef __attribute__((ext_vector_type(8))) short s16x8;
typedef __attribute__((ext_vector_type(4))) float f32x4;

#define BATCH 32768
#define LSEQ 128
#define NJT 16
#define NFRAG 28                           // frags per j-tile: r,z,hn x 9ks + in x 1
#define WFRAG_SHORTS (NJT * NFRAG * 512)   // 229376 shorts
#define WFC_SHORTS 4096
#define XT_OFF_BYTES ((WFRAG_SHORTS + WFC_SHORTS) * 2)        // 466944
#define WS_NEED_XT (XT_OFF_BYTES + BATCH * LSEQ * 4)          // ~16.45 MB

#define HBUF_SHORTS (128 * 256)                               // 64 KiB per buffer
#define LDS_BYTES (2 * HBUF_SHORTS * 2 + WFC_SHORTS * 2)      // 139264 B = 136 KiB

#define L2E 1.4426950408889634f
#define LN2 0.6931471805599453f

__device__ __forceinline__ unsigned short f2b(float f) {
  unsigned u = __float_as_uint(f);
  u += 0x7FFFu + ((u >> 16) & 1u);     // round-to-nearest-even bf16
  return (unsigned short)(u >> 16);
}

// Native-transcendental wrappers (register-only VALU asm; schedulable, CSE-able)
__device__ __forceinline__ float exp2n(float x) { float r; asm("v_exp_f32 %0, -%1" : "=v"(r) : "v"(x)); return r; }  // 2^-x
__device__ __forceinline__ float exp2p(float x) { float r; asm("v_exp_f32 %0, %1" : "=v"(r) : "v"(x)); return r; }   // 2^x
__device__ __forceinline__ float rcp_(float x)  { float r; asm("v_rcp_f32 %0, %1" : "=v"(r) : "v"(x)); return r; }
__device__ __forceinline__ float log2_(float x) { float r; asm("v_log_f32 %0, %1" : "=v"(r) : "v"(x)); return r; }
__device__ __forceinline__ unsigned cvtpk(float lo, float hi) {
  unsigned r; asm("v_cvt_pk_bf16_f32 %0, %1, %2" : "=v"(r) : "v"(lo), "v"(hi)); return r;
}

// Pack W into MFMA A-fragment order, augmented K: k256=x coeff, k257=bias.
// Gate scales folded in: r,z rows x log2e; n rows (W_hn, b_hh_n, W_in, b_in) x 2*log2e.
// Fragment (jt, f): f = g*9+ks (g=0 r,1 z,2 hn), f==27: "in" tile (unused now).
// Element (lane, e): A-row = jt*16 + (lane&15), k = ks*32 + (lane>>4)*8 + e.
__global__ void gru_prep(const float* __restrict__ Wih, const float* __restrict__ Whh,
                         const float* __restrict__ bih, const float* __restrict__ bhh,
                         const float* __restrict__ Wfc,
                         unsigned short* __restrict__ wfrag,
                         unsigned short* __restrict__ wfc16) {
  int t = blockIdx.x * 256 + threadIdx.x;
  if (t < WFRAG_SHORTS) {
    int e = t & 7, lane = (t >> 3) & 63, fl = t >> 9;
    int f = fl % NFRAG, jt = fl / NFRAG;
    int m = lane & 15, gl = lane >> 4;
    float val = 0.f;
    if (f < 27) {
      int g = f / 9, ks = f % 9;
      int row = g * 256 + jt * 16 + m;
      int k = ks * 32 + gl * 8 + e;
      float sc = (g == 2) ? 2.f * L2E : L2E;
      if (k < 256) val = Whh[row * 256 + k] * sc;
      else if (k == 256) val = (g == 2) ? 0.f : Wih[row] * sc;
      else if (k == 257) val = ((g == 2) ? bhh[row] : (bih[row] + bhh[row])) * sc;
    }
    wfrag[t] = f2b(val);
  } else if (t < WFRAG_SHORTS + WFC_SHORTS) { // W_fc -> bf16 [16][256] row-major, x log2e
    int t2 = t - WFRAG_SHORTS;
    wfc16[t2] = f2b(Wfc[t2] * L2E);
  }
}

// Tiled transpose x[B][L] -> xT[L][B] so per-step column reads are coalesced.
__global__ void x_transpose(const int* __restrict__ x, int* __restrict__ xT) {
  __shared__ int tile[32][33];
  int l0 = blockIdx.x * 32, b0 = blockIdx.y * 32;
  for (int r = threadIdx.y; r < 32; r += 8)
    tile[r][threadIdx.x] = x[(b0 + r) * LSEQ + l0 + threadIdx.x];
  __syncthreads();
  for (int r = threadIdx.y; r < 32; r += 8)
    xT[(l0 + r) * BATCH + b0 + threadIdx.x] = tile[threadIdx.x][r];
}

// LDS h layout: [row][256 shorts], column rotated by (row&15)*8 shorts.
__device__ __forceinline__ int haddr(int lrow, int col_s) {
  return lrow * 256 + ((col_s + ((lrow & 15) << 3)) & 255);
}

template <int XT>
__global__ __attribute__((amdgpu_waves_per_eu(2, 2))) __launch_bounds__(512)
void gru_main(const int* __restrict__ x, const int* __restrict__ xTr,
              const unsigned short* __restrict__ wfrag,
              const unsigned short* __restrict__ wfc16,
              const float* __restrict__ Wih, const float* __restrict__ bih,
              const float* __restrict__ bfc, float* __restrict__ out) {
  extern __shared__ unsigned short smem_us[];
  unsigned short* h0 = smem_us;                    // 64 KiB
  unsigned short* h1 = smem_us + HBUF_SHORTS;      // 64 KiB
  unsigned short* wl = smem_us + 2 * HBUF_SHORTS;  // 8 KiB W_fc, swizzled

  const int tid = threadIdx.x;
  const int lane = tid & 63;
  const int wv = tid >> 6;      // wave 0..7
  const int q = lane >> 4;      // 0..3
  const int b = lane & 15;
  const int bbase = blockIdx.x * 128;

  { // zero h0 (h1 fully written in step 0 before any read)
    unsigned int* p = (unsigned int*)h0;
#pragma unroll
    for (int r = 0; r < 32; ++r) p[tid + r * 512] = 0u;
  }
  // copy W_fc into LDS with the same rot-8 swizzle (row = logit index)
  for (int t = tid; t < WFC_SHORTS; t += 512) {
    int m = t >> 8, col = t & 255;
    wl[haddr(m, col)] = wfc16[t];
  }

  // i_n scalar coefficients for both phases: w_in, b_in x 2*log2e (persistent)
  float win0[4], bin0[4], win1[4], bin1[4];
#pragma unroll
  for (int r = 0; r < 4; ++r) {
    int j0 = 512 + wv * 16 + q * 4 + r;
    int j1 = 512 + (wv + 8) * 16 + q * 4 + r;
    win0[r] = Wih[j0] * (2.f * L2E);  bin0[r] = bih[j0] * (2.f * L2E);
    win1[r] = Wih[j1] * (2.f * L2E);  bin1[r] = bih[j1] * (2.f * L2E);
  }
  float bfc4[4];
#pragma unroll
  for (int r = 0; r < 4; ++r) bfc4[r] = bfc[q * 4 + r] * L2E;

  float lp = 0.f;   // accumulated in base-2 units; x ln2 at the end
  __syncthreads();

#pragma unroll 1
  for (int i = 0; i < LSEQ; ++i) {
    const unsigned short* rd = (i & 1) ? h1 : h0;   // h_{i-1}
    unsigned short* wr = (i & 1) ? h0 : h1;         // h_i

    // launder weight pointer so frag loads are not hoisted across steps
    unsigned long wfu = (unsigned long)wfrag;
    asm volatile("" : "+s"(wfu));
    const unsigned short* wf = (const unsigned short*)wfu;

    // x inputs for this step (x_in = x[:, i-1], 0 at i==0); values 0..15 exact
    float xin8[8];
    unsigned xlo[8];
#pragma unroll
    for (int bt = 0; bt < 8; ++bt) {
      float xv;
      if (XT) xv = (i > 0) ? (float)xTr[(i - 1) * BATCH + bbase + bt * 16 + b] : 0.f;
      else    xv = (i > 0) ? (float)x[(bbase + bt * 16 + b) * LSEQ + i - 1] : 0.f;
      xin8[bt] = xv;
      // B-frag low word for aug tile: k=256 -> bf16(x), k=257 -> 1.0 (only q==0)
      xlo[bt] = (q == 0) ? ((__float_as_uint(xv) >> 16) | 0x3F800000u) : 0u;
    }

#pragma unroll 1
    for (int ph = 0; ph < 2; ++ph) {
      const int jt = wv + 8 * ph;
      const unsigned short* fb = wf + (jt * NFRAG * 64 + lane) * 8;

      f32x4 aR[8], aZ[8], aH[8];
      const f32x4 Z = {0.f, 0.f, 0.f, 0.f};

      // issue aug frags (f=8,17,26) and ks=0 frags together
      s16x8 ar = *(const s16x8*)(fb + 8 * 512);
      s16x8 az = *(const s16x8*)(fb + 17 * 512);
      s16x8 ah = *(const s16x8*)(fb + 26 * 512);
      s16x8 cr = *(const s16x8*)(fb);
      s16x8 cz = *(const s16x8*)(fb + 9 * 512);
      s16x8 ch = *(const s16x8*)(fb + 18 * 512);

      // aug-first: initializes accumulators (C = 0), gi contribution done here
#pragma unroll
      for (int bt = 0; bt < 8; ++bt) {
        union { unsigned u[4]; s16x8 v; } xf;
        xf.u[0] = xlo[bt]; xf.u[1] = 0u; xf.u[2] = 0u; xf.u[3] = 0u;
        aR[bt] = __builtin_amdgcn_mfma_f32_16x16x32_bf16(ar, xf.v, Z, 0, 0, 0);
        aZ[bt] = __builtin_amdgcn_mfma_f32_16x16x32_bf16(az, xf.v, Z, 0, 0, 0);
        aH[bt] = __builtin_amdgcn_mfma_f32_16x16x32_bf16(ah, xf.v, Z, 0, 0, 0);
      }

      auto burst = [&](s16x8 A0, s16x8 A1, s16x8 A2, int ks) {
#pragma unroll
        for (int bt = 0; bt < 8; ++bt) {
          const s16x8 hb = *(const s16x8*)&rd[haddr(bt * 16 + b, 32 * ks + 8 * q)];
          aR[bt] = __builtin_amdgcn_mfma_f32_16x16x32_bf16(A0, hb, aR[bt], 0, 0, 0);
          aZ[bt] = __builtin_amdgcn_mfma_f32_16x16x32_bf16(A1, hb, aZ[bt], 0, 0, 0);
          aH[bt] = __builtin_amdgcn_mfma_f32_16x16x32_bf16(A2, hb, aH[bt], 0, 0, 0);
        }
      };

      // K-loop with depth-1 prefetch
#pragma unroll 1
      for (int ks = 0; ks < 7; ++ks) {
        s16x8 nr = *(const s16x8*)(fb + (ks + 1) * 512);
        s16x8 nz = *(const s16x8*)(fb + (ks + 10) * 512);
        s16x8 nh = *(const s16x8*)(fb + (ks + 19) * 512);
        burst(cr, cz, ch, ks);
        cr = nr; cz = nz; ch = nh;
      }
      burst(cr, cz, ch, 7);

      // gate epilogue + direct h write (phase-local; safe with 1 barrier/step)
      const float wcA = ph ? win1[0] : win0[0], wcB = ph ? win1[1] : win0[1];
      const float wcC = ph ? win1[2] : win0[2], wcD = ph ? win1[3] : win0[3];
      const float bcA = ph ? bin1[0] : bin0[0], bcB = ph ? bin1[1] : bin0[1];
      const float bcC = ph ? bin1[2] : bin0[2], bcD = ph ? bin1[3] : bin0[3];
#pragma unroll
      for (int bt = 0; bt < 8; ++bt) {
        const int lrow = bt * 16 + b;
        const uint2 hp = *(const uint2*)&rd[haddr(lrow, 16 * jt + 4 * q)];
        const float xv = xin8[bt];
        const float inr[4] = {fmaf(xv, wcA, bcA), fmaf(xv, wcB, bcB),
                              fmaf(xv, wcC, bcC), fmaf(xv, wcD, bcD)};
        const float hpv[4] = {
            __uint_as_float(hp.x << 16), __uint_as_float(hp.x & 0xFFFF0000u),
            __uint_as_float(hp.y << 16), __uint_as_float(hp.y & 0xFFFF0000u)};
        float hv[4];
#pragma unroll
        for (int r = 0; r < 4; ++r) {
          float rr = rcp_(1.f + exp2n(aR[bt][r]));     // sigmoid via 2^-a
          float zz = rcp_(1.f + exp2n(aZ[bt][r]));
          float y  = fmaf(rr, aH[bt][r], inr[r]);      // 2*log2e*(i_n + r*h_n)
          float u  = rcp_(1.f + exp2p(y));
          float nn = fmaf(-2.f, u, 1.f);               // tanh
          hv[r] = fmaf(zz, hpv[r] - nn, nn);           // (1-z)*n + z*h
        }
        *(uint2*)&wr[haddr(lrow, 16 * jt + 4 * q)] =
            make_uint2(cvtpk(hv[0], hv[1]), cvtpk(hv[2], hv[3]));
      }
    }

    __syncthreads();   // h_i visible everywhere; only barrier per step

    { // FC + base-2 log_softmax + gather; wave wv handles batch tile bt == wv
      const int lrow = wv * 16 + b;
      const int grow = bbase + lrow;
      f32x4 fa = {bfc4[0], bfc4[1], bfc4[2], bfc4[3]};
#pragma unroll
      for (int ks = 0; ks < 8; ++ks) {
        s16x8 wfcf = *(const s16x8*)&wl[haddr(b, 32 * ks + 8 * q)];
        s16x8 hb = *(const s16x8*)&wr[haddr(lrow, 32 * ks + 8 * q)];
        fa = __builtin_amdgcn_mfma_f32_16x16x32_bf16(wfcf, hb, fa, 0, 0, 0);
      }
      int tgt = XT ? xTr[i * BATCH + grow] : x[grow * LSEQ + i];
      float l0 = fa[0], l1 = fa[1], l2 = fa[2], l3 = fa[3];
      float mx = fmaxf(fmaxf(l0, l1), fmaxf(l2, l3));
      mx = fmaxf(mx, __shfl_xor(mx, 16));
      mx = fmaxf(mx, __shfl_xor(mx, 32));
      float se = exp2p(l0 - mx) + exp2p(l1 - mx) + exp2p(l2 - mx) + exp2p(l3 - mx);
      se += __shfl_xor(se, 16);
      se += __shfl_xor(se, 32);
      float v01 = (tgt & 1) ? l1 : l0;
      float v23 = (tgt & 1) ? l3 : l2;
      float vs = (tgt & 2) ? v23 : v01;
      float contrib = (q == (tgt >> 2)) ? vs : 0.f;
      contrib += __shfl_xor(contrib, 16);
      contrib += __shfl_xor(contrib, 32);
      lp += contrib - mx - log2_(se);
    }
  }

  if (q == 0) out[bbase + wv * 16 + b] = lp * LN2;
}

extern "C" void kernel_launch(void* const* d_in, const int* in_sizes, int n_in,
                              void* d_out, int out_size, void* d_ws, size_t ws_size,
                              hipStream_t stream) {
  (void)in_sizes; (void)n_in; (void)out_size;
  const int*   x   = (const int*)d_in[0];
  const float* Wih = (const float*)d_in[1];
  const float* Whh = (const float*)d_in[2];
  const float* bih = (const float*)d_in[3];
  const float* bhh = (const float*)d_in[4];
  const float* Wfc = (const float*)d_in[5];
  const float* bfc = (const float*)d_in[6];
  float* out = (float*)d_out;

  unsigned short* wfrag = (unsigned short*)d_ws;
  unsigned short* wfc16 = wfrag + WFRAG_SHORTS;
  int* xT = (int*)((char*)d_ws + XT_OFF_BYTES);

  gru_prep<<<dim3(912), dim3(256), 0, stream>>>(Wih, Whh, bih, bhh, Wfc, wfrag, wfc16);

  if (ws_size >= (size_t)WS_NEED_XT) {
    x_transpose<<<dim3(LSEQ / 32, BATCH / 32), dim3(32, 8), 0, stream>>>(x, xT);
    hipFuncSetAttribute((const void*)gru_main<1>,
                        hipFuncAttributeMaxDynamicSharedMemorySize, LDS_BYTES);
    gru_main<1><<<dim3(256), dim3(512), LDS_BYTES, stream>>>(x, xT, wfrag, wfc16,
                                                             Wih, bih, bfc, out);
  } else {
    hipFuncSetAttribute((const void*)gru_main<0>,
                        hipFuncAttributeMaxDynamicSharedMemorySize, LDS_BYTES);
    gru_main<0><<<dim3(256), dim3(512), LDS_BYTES, stream>>>(x, x, wfrag, wfc16,
                                                             Wih, bih, bfc, out);
  }
}